// Round 9
// baseline (462.507 us; speedup 1.0000x reference)
//
#include <hip/hip_runtime.h>
#include <math.h>

#define NS 4
#define HDIM 1024
#define DDIM 4096           // NS*HDIM
#define TA 4                // tokens per block in mhc_gates
#define HC_EPS_F 1e-6f
#define NORM_EPS_F 1e-6f

__device__ __forceinline__ float frcp(float v) { return __builtin_amdgcn_rcpf(v); }

// ============ K1: dots + sinkhorn -> gates[tok][24]. 1-deep x+fn prefetch, <=128 VGPR. ============
// gates layout: [0..3]=h_pre, [4..7]=h_post, [8..23]=h_res (i*4+j)
__launch_bounds__(256, 4)   // cap 128 VGPR; demand ~117 -> no spill, 4 blocks/CU
__global__ void mhc_gates(const float* __restrict__ x,
                          const float* __restrict__ hc_fn,
                          const float* __restrict__ hc_scale,
                          const float* __restrict__ hc_base,
                          float* __restrict__ gates) {
  __shared__ float w_s[25][TA];        // 24 weights + ssq per token (400 B)

  const int tid  = threadIdx.x;
  const int lane = tid & 63;
  const int wave = tid >> 6;
  const long long tok0 = (long long)blockIdx.x * TA;

  const float4* xb[TA];
  #pragma unroll
  for (int t = 0; t < TA; ++t)
    xb[t] = (const float4*)(x + (tok0 + t) * DDIM);

  const int mb = wave * 6;             // wave owns m in [6w, 6w+6)
  const float4* fn4[6];
  #pragma unroll
  for (int m = 0; m < 6; ++m)
    fn4[m] = (const float4*)(hc_fn + (long long)(mb + m) * DDIM);

  float acc[6][TA];
  #pragma unroll
  for (int m = 0; m < 6; ++m)
    #pragma unroll
    for (int t = 0; t < TA; ++t) acc[m][t] = 0.f;
  float myssq = 0.f;                   // wave w accumulates sumsq of token w

  // preload iteration 0 (x and fn)
  float4 c_x[TA], c_f[6];
  #pragma unroll
  for (int t = 0; t < TA; ++t) c_x[t] = xb[t][lane];
  #pragma unroll
  for (int m = 0; m < 6; ++m) c_f[m] = fn4[m][lane];

  #pragma unroll 2
  for (int it = 0; it < 16; ++it) {
    // issue ALL of next iteration's loads first (10 in flight during FMAs)
    float4 n_x[TA], n_f[6];
    if (it < 15) {
      const int nfl = it * 64 + 64 + lane;
      #pragma unroll
      for (int t = 0; t < TA; ++t) n_x[t] = xb[t][nfl];
      #pragma unroll
      for (int m = 0; m < 6; ++m) n_f[m] = fn4[m][nfl];
    }
    #pragma unroll
    for (int t = 0; t < TA; ++t) {
      if (wave == t)                   // compile-time t, wave-uniform branch
        myssq = fmaf(c_x[t].x, c_x[t].x, fmaf(c_x[t].y, c_x[t].y,
                fmaf(c_x[t].z, c_x[t].z, fmaf(c_x[t].w, c_x[t].w, myssq))));
      #pragma unroll
      for (int m = 0; m < 6; ++m)
        acc[m][t] = fmaf(c_x[t].x, c_f[m].x,
                    fmaf(c_x[t].y, c_f[m].y,
                    fmaf(c_x[t].z, c_f[m].z,
                    fmaf(c_x[t].w, c_f[m].w, acc[m][t]))));
    }
    if (it < 15) {
      #pragma unroll
      for (int t = 0; t < TA; ++t) c_x[t] = n_x[t];
      #pragma unroll
      for (int m = 0; m < 6; ++m) c_f[m] = n_f[m];
    }
  }

  // butterfly reduce -> LDS (lane 0 of each wave writes its 6 m-rows + its token's ssq)
  #pragma unroll
  for (int m = 0; m < 6; ++m)
    #pragma unroll
    for (int t = 0; t < TA; ++t) {
      float v = acc[m][t];
      #pragma unroll
      for (int off = 32; off > 0; off >>= 1) v += __shfl_xor(v, off, 64);
      if (lane == 0) w_s[mb + m][t] = v;
    }
  {
    float v = myssq;
    #pragma unroll
    for (int off = 32; off > 0; off >>= 1) v += __shfl_xor(v, off, 64);
    if (lane == 0) w_s[24][wave] = v;
  }
  __syncthreads();

  // sinkhorn + gates on wave 0: 16 lanes per token, 4 tokens (= 64 lanes exactly)
  if (wave == 0) {
    const int tt = lane >> 4;
    const int e  = lane & 15;          // i*4 + j
    const float rs = rsqrtf(w_s[24][tt] * (1.0f / DDIM) + NORM_EPS_F);
    const float s0 = hc_scale[0], s1 = hc_scale[1], s2 = hc_scale[2];

    float h = w_s[8 + e][tt] * rs * s2 + hc_base[8 + e];
    // row softmax over j (quad shuffles) + eps
    float mx = fmaxf(h, __shfl_xor(h, 1, 4));
    mx = fmaxf(mx, __shfl_xor(mx, 2, 4));
    float ex = expf(h - mx);
    float sm = ex + __shfl_xor(ex, 1, 4);
    sm += __shfl_xor(sm, 2, 4);
    h = ex * frcp(sm) + HC_EPS_F;
    // column normalize (sum over i: xor 4,8 within 16)
    float cs = h + __shfl_xor(h, 4, 16);
    cs += __shfl_xor(cs, 8, 16);
    h *= frcp(cs + HC_EPS_F);
    #pragma unroll 1
    for (int itn = 0; itn < 19; ++itn) {
      float rsum = h + __shfl_xor(h, 1, 4);
      rsum += __shfl_xor(rsum, 2, 4);
      h *= frcp(rsum + HC_EPS_F);
      float csum = h + __shfl_xor(h, 4, 16);
      csum += __shfl_xor(csum, 8, 16);
      h *= frcp(csum + HC_EPS_F);
    }
    float* g = gates + (tok0 + tt) * 24;
    g[8 + e] = h;
    if (e < NS) {
      const float wp = w_s[e][tt] * rs;
      g[e] = frcp(1.0f + expf(-(wp * s0 + hc_base[e]))) + HC_EPS_F;
      const float wq = w_s[NS + e][tt] * rs;
      g[NS + e] = 2.0f * frcp(1.0f + expf(-(wq * s1 + hc_base[NS + e])));
    }
  }
}

// ============ K2: gates + x -> out (pure stream, measured ~21us) ============
__launch_bounds__(256, 8)
__global__ void mhc_out(const float* __restrict__ x,
                        const float* __restrict__ gates,
                        float* __restrict__ out) {
  const long long token = blockIdx.x;
  const int q = threadIdx.x;           // float4 index in [0,256)

  const float* g = gates + token * 24; // uniform address -> scalar loads
  float hp[NS], hq[NS], hr[NS][NS];
  #pragma unroll
  for (int i = 0; i < NS; ++i) {
    hp[i] = g[i];
    hq[i] = g[NS + i];
    #pragma unroll
    for (int j = 0; j < NS; ++j) hr[i][j] = g[8 + i * NS + j];
  }

  const float4* xb = (const float4*)(x + token * DDIM);
  float4 xv[NS];
  #pragma unroll
  for (int i = 0; i < NS; ++i) xv[i] = xb[i * 256 + q];

  float4 y;
  y.x = hp[0]*xv[0].x + hp[1]*xv[1].x + hp[2]*xv[2].x + hp[3]*xv[3].x;
  y.y = hp[0]*xv[0].y + hp[1]*xv[1].y + hp[2]*xv[2].y + hp[3]*xv[3].y;
  y.z = hp[0]*xv[0].z + hp[1]*xv[1].z + hp[2]*xv[2].z + hp[3]*xv[3].z;
  y.w = hp[0]*xv[0].w + hp[1]*xv[1].w + hp[2]*xv[2].w + hp[3]*xv[3].w;

  float4* ob = (float4*)(out + token * DDIM);
  #pragma unroll
  for (int n = 0; n < NS; ++n) {
    float4 o;
    o.x = hq[n]*y.x + hr[0][n]*xv[0].x + hr[1][n]*xv[1].x + hr[2][n]*xv[2].x + hr[3][n]*xv[3].x;
    o.y = hq[n]*y.y + hr[0][n]*xv[0].y + hr[1][n]*xv[1].y + hr[2][n]*xv[2].y + hr[3][n]*xv[3].y;
    o.z = hq[n]*y.z + hr[0][n]*xv[0].z + hr[1][n]*xv[1].z + hr[2][n]*xv[2].z + hr[3][n]*xv[3].z;
    o.w = hq[n]*y.w + hr[0][n]*xv[0].w + hr[1][n]*xv[1].w + hr[2][n]*xv[2].w + hr[3][n]*xv[3].w;
    ob[n * 256 + q] = o;
  }
}

extern "C" void kernel_launch(void* const* d_in, const int* in_sizes, int n_in,
                              void* d_out, int out_size, void* d_ws, size_t ws_size,
                              hipStream_t stream) {
  const float* x        = (const float*)d_in[0];
  const float* hc_fn    = (const float*)d_in[1];
  const float* hc_scale = (const float*)d_in[2];
  const float* hc_base  = (const float*)d_in[3];
  float* out   = (float*)d_out;
  float* gates = (float*)d_ws;         // ntok*24*4 = 786 KB (proven within ws_size)

  const int ntok = in_sizes[0] / DDIM; // B*S = 8192
  mhc_gates<<<ntok / TA, 256, 0, stream>>>(x, hc_fn, hc_scale, hc_base, gates);
  mhc_out<<<ntok, 256, 0, stream>>>(x, gates, out);
}

// Round 10
// 109.433 us; speedup vs baseline: 4.2264x; 4.2264x over previous
//
#include <hip/hip_runtime.h>
#include <math.h>

#define NS 4
#define HDIM 1024
#define DDIM 4096           // NS*HDIM
#define TA 4                // tokens per block in mhc_gates
#define HC_EPS_F 1e-6f
#define NORM_EPS_F 1e-6f

__device__ __forceinline__ float frcp(float v) { return __builtin_amdgcn_rcpf(v); }

// ============ K1: dots + sinkhorn -> gates[tok][24]. x 1-deep prefetch, ~110 VGPR. ============
// gates layout: [0..3]=h_pre, [4..7]=h_post, [8..23]=h_res (i*4+j)
// NOTE toolchain empirical law: 2nd launch_bounds arg -> VGPR cap = 256/arg
// ((256,2)=128, (256,3)=84, (256,4)=64 — measured R7/R8/R9). Demand here ~110.
__launch_bounds__(256, 2)
__global__ void mhc_gates(const float* __restrict__ x,
                          const float* __restrict__ hc_fn,
                          const float* __restrict__ hc_scale,
                          const float* __restrict__ hc_base,
                          float* __restrict__ gates) {
  __shared__ float w_s[25][TA];        // 24 weights + ssq per token (400 B)

  const int tid  = threadIdx.x;
  const int lane = tid & 63;
  const int wave = tid >> 6;
  const long long tok0 = (long long)blockIdx.x * TA;

  const float4* xb[TA];
  #pragma unroll
  for (int t = 0; t < TA; ++t)
    xb[t] = (const float4*)(x + (tok0 + t) * DDIM);

  const int mb = wave * 6;             // wave owns m in [6w, 6w+6)
  const float4* fn4[6];
  #pragma unroll
  for (int m = 0; m < 6; ++m)
    fn4[m] = (const float4*)(hc_fn + (long long)(mb + m) * DDIM);

  float acc[6][TA];
  #pragma unroll
  for (int m = 0; m < 6; ++m)
    #pragma unroll
    for (int t = 0; t < TA; ++t) acc[m][t] = 0.f;
  float myssq = 0.f;                   // wave w accumulates sumsq of token w

  // preload iteration 0 of x (the HBM stream; fn is L2-resident, loaded in-loop)
  float4 c_x[TA];
  #pragma unroll
  for (int t = 0; t < TA; ++t) c_x[t] = xb[t][lane];

  #pragma unroll 2
  for (int it = 0; it < 16; ++it) {
    const int fl = it * 64 + lane;
    // next iteration's x loads first (4 dwordx4 in flight across the FMA block)
    float4 n_x[TA];
    if (it < 15) {
      #pragma unroll
      for (int t = 0; t < TA; ++t) n_x[t] = xb[t][fl + 64];
    }
    // current iteration's fn loads (L2-hit ~200cy, covered by 4-wave TLP)
    float4 c_f[6];
    #pragma unroll
    for (int m = 0; m < 6; ++m) c_f[m] = fn4[m][fl];

    #pragma unroll
    for (int t = 0; t < TA; ++t) {
      if (wave == t)                   // compile-time t, wave-uniform branch
        myssq = fmaf(c_x[t].x, c_x[t].x, fmaf(c_x[t].y, c_x[t].y,
                fmaf(c_x[t].z, c_x[t].z, fmaf(c_x[t].w, c_x[t].w, myssq))));
      #pragma unroll
      for (int m = 0; m < 6; ++m)
        acc[m][t] = fmaf(c_x[t].x, c_f[m].x,
                    fmaf(c_x[t].y, c_f[m].y,
                    fmaf(c_x[t].z, c_f[m].z,
                    fmaf(c_x[t].w, c_f[m].w, acc[m][t]))));
    }
    if (it < 15) {
      #pragma unroll
      for (int t = 0; t < TA; ++t) c_x[t] = n_x[t];
    }
  }

  // butterfly reduce -> LDS (lane 0 of each wave writes its 6 m-rows + its token's ssq)
  #pragma unroll
  for (int m = 0; m < 6; ++m)
    #pragma unroll
    for (int t = 0; t < TA; ++t) {
      float v = acc[m][t];
      #pragma unroll
      for (int off = 32; off > 0; off >>= 1) v += __shfl_xor(v, off, 64);
      if (lane == 0) w_s[mb + m][t] = v;
    }
  {
    float v = myssq;
    #pragma unroll
    for (int off = 32; off > 0; off >>= 1) v += __shfl_xor(v, off, 64);
    if (lane == 0) w_s[24][wave] = v;
  }
  __syncthreads();

  // sinkhorn + gates on wave 0: 16 lanes per token, 4 tokens (= 64 lanes exactly)
  if (wave == 0) {
    const int tt = lane >> 4;
    const int e  = lane & 15;          // i*4 + j
    const float rs = rsqrtf(w_s[24][tt] * (1.0f / DDIM) + NORM_EPS_F);
    const float s0 = hc_scale[0], s1 = hc_scale[1], s2 = hc_scale[2];

    float h = w_s[8 + e][tt] * rs * s2 + hc_base[8 + e];
    // row softmax over j (quad shuffles) + eps
    float mx = fmaxf(h, __shfl_xor(h, 1, 4));
    mx = fmaxf(mx, __shfl_xor(mx, 2, 4));
    float ex = expf(h - mx);
    float sm = ex + __shfl_xor(ex, 1, 4);
    sm += __shfl_xor(sm, 2, 4);
    h = ex * frcp(sm) + HC_EPS_F;
    // column normalize (sum over i: xor 4,8 within 16)
    float cs = h + __shfl_xor(h, 4, 16);
    cs += __shfl_xor(cs, 8, 16);
    h *= frcp(cs + HC_EPS_F);
    #pragma unroll 1
    for (int itn = 0; itn < 19; ++itn) {
      float rsum = h + __shfl_xor(h, 1, 4);
      rsum += __shfl_xor(rsum, 2, 4);
      h *= frcp(rsum + HC_EPS_F);
      float csum = h + __shfl_xor(h, 4, 16);
      csum += __shfl_xor(csum, 8, 16);
      h *= frcp(csum + HC_EPS_F);
    }
    float* g = gates + (tok0 + tt) * 24;
    g[8 + e] = h;
    if (e < NS) {
      const float wp = w_s[e][tt] * rs;
      g[e] = frcp(1.0f + expf(-(wp * s0 + hc_base[e]))) + HC_EPS_F;
      const float wq = w_s[NS + e][tt] * rs;
      g[NS + e] = 2.0f * frcp(1.0f + expf(-(wq * s1 + hc_base[NS + e])));
    }
  }
}

// ============ K2: gates + x -> out (pure stream, at write roofline ~21us) ============
__launch_bounds__(256, 8)
__global__ void mhc_out(const float* __restrict__ x,
                        const float* __restrict__ gates,
                        float* __restrict__ out) {
  const long long token = blockIdx.x;
  const int q = threadIdx.x;           // float4 index in [0,256)

  const float* g = gates + token * 24; // uniform address -> scalar loads
  float hp[NS], hq[NS], hr[NS][NS];
  #pragma unroll
  for (int i = 0; i < NS; ++i) {
    hp[i] = g[i];
    hq[i] = g[NS + i];
    #pragma unroll
    for (int j = 0; j < NS; ++j) hr[i][j] = g[8 + i * NS + j];
  }

  const float4* xb = (const float4*)(x + token * DDIM);
  float4 xv[NS];
  #pragma unroll
  for (int i = 0; i < NS; ++i) xv[i] = xb[i * 256 + q];

  float4 y;
  y.x = hp[0]*xv[0].x + hp[1]*xv[1].x + hp[2]*xv[2].x + hp[3]*xv[3].x;
  y.y = hp[0]*xv[0].y + hp[1]*xv[1].y + hp[2]*xv[2].y + hp[3]*xv[3].y;
  y.z = hp[0]*xv[0].z + hp[1]*xv[1].z + hp[2]*xv[2].z + hp[3]*xv[3].z;
  y.w = hp[0]*xv[0].w + hp[1]*xv[1].w + hp[2]*xv[2].w + hp[3]*xv[3].w;

  float4* ob = (float4*)(out + token * DDIM);
  #pragma unroll
  for (int n = 0; n < NS; ++n) {
    float4 o;
    o.x = hq[n]*y.x + hr[0][n]*xv[0].x + hr[1][n]*xv[1].x + hr[2][n]*xv[2].x + hr[3][n]*xv[3].x;
    o.y = hq[n]*y.y + hr[0][n]*xv[0].y + hr[1][n]*xv[1].y + hr[2][n]*xv[2].y + hr[3][n]*xv[3].y;
    o.z = hq[n]*y.z + hr[0][n]*xv[0].z + hr[1][n]*xv[1].z + hr[2][n]*xv[2].z + hr[3][n]*xv[3].z;
    o.w = hq[n]*y.w + hr[0][n]*xv[0].w + hr[1][n]*xv[1].w + hr[2][n]*xv[2].w + hr[3][n]*xv[3].w;
    ob[n * 256 + q] = o;
  }
}

extern "C" void kernel_launch(void* const* d_in, const int* in_sizes, int n_in,
                              void* d_out, int out_size, void* d_ws, size_t ws_size,
                              hipStream_t stream) {
  const float* x        = (const float*)d_in[0];
  const float* hc_fn    = (const float*)d_in[1];
  const float* hc_scale = (const float*)d_in[2];
  const float* hc_base  = (const float*)d_in[3];
  float* out   = (float*)d_out;
  float* gates = (float*)d_ws;         // ntok*24*4 = 786 KB (proven within ws_size)

  const int ntok = in_sizes[0] / DDIM; // B*S = 8192
  mhc_gates<<<ntok / TA, 256, 0, stream>>>(x, hc_fn, hc_scale, hc_base, gates);
  mhc_out<<<ntok, 256, 0, stream>>>(x, gates, out);
}